// Round 1
// baseline (2726.847 us; speedup 1.0000x reference)
//
#include <hip/hip_runtime.h>
#include <hip/hip_bf16.h>
#include <stdint.h>

// AspectSent forward on MI355X.
// Pipeline: embed -> [gi GEMM -> persistent GRU]x2 layers (f+b dirs) -> im2col
// -> conv GEMM(+relu) -> avg -> tri -> CRF -> sent_v -> loss.
// All matmuls bf16 MFMA 16x16x32, f32 accumulate. GRU: whh VGPR-resident
// (48 B-frags/wave), h state in LDS (f32 + bf16 mirror), 2 barriers/step.

#define TT 100
#define BB 128

typedef short s16;
typedef __attribute__((ext_vector_type(8))) short s16x8;
typedef __attribute__((ext_vector_type(4))) float f32x4;

__device__ __forceinline__ float bf2f(s16 s) {
  return __uint_as_float(((unsigned)(unsigned short)s) << 16);
}
__device__ __forceinline__ s16 f2bf(float f) {
  __hip_bfloat16 h = __float2bfloat16(f);
  return *(s16*)&h;
}
__device__ __forceinline__ float sigf(float x) { return 1.f / (1.f + __expf(-x)); }
__device__ __forceinline__ float tanhfast(float x) { return 2.f / (1.f + __expf(-2.f * x)) - 1.f; }
__device__ __forceinline__ float lse2(float a, float b) {
  float m = fmaxf(a, b);
  return m + logf(expf(a - m) + expf(b - m));
}

// ---------------- prep kernels ----------------

// f32 (768x350) -> bf16 (768x352), zero-pad last 2 cols
__global__ void k_cvtpad(const float* __restrict__ src, s16* __restrict__ dst) {
  int idx = blockIdx.x * 256 + threadIdx.x;           // 768*352
  if (idx >= 768 * 352) return;
  int n = idx / 352, k = idx % 352;
  dst[idx] = (k < 350) ? f2bf(src[n * 350 + k]) : (s16)0;
}

__global__ void k_cvt(const float* __restrict__ src, s16* __restrict__ dst, int n) {
  int idx = blockIdx.x * 256 + threadIdx.x;
  if (idx < n) dst[idx] = f2bf(src[idx]);
}

// whh (768x256 f32) -> MFMA B-fragment layout bf16.
// wf[((w*48 + f)*64 + l)*8 + i] = whh[col*256 + k],
//   f = nt*8+kt, col = 96w+16nt+(l&15), k = 32kt+8*(l>>4)+i
__global__ void k_wfrag(const float* __restrict__ whh, s16* __restrict__ wf) {
  int tid = blockIdx.x * 256 + threadIdx.x;           // 196608
  if (tid >= 196608) return;
  int w = tid / 24576, rem = tid % 24576;
  int f = rem / 512, rem2 = rem % 512;
  int l = rem2 / 8, i = rem2 % 8;
  int nt = f / 8, kt = f % 8;
  int col = 96 * w + 16 * nt + (l & 15);
  int k = 32 * kt + 8 * (l >> 4) + i;
  wf[tid] = f2bf(whh[col * 256 + k]);
}

// conv_w (512,512,3) -> w2 bf16 [512][1536], w2[o][w*512+i] = conv_w[o,i,w]
__global__ void k_w2(const float* __restrict__ cw, s16* __restrict__ w2) {
  int idx = blockIdx.x * 256 + threadIdx.x;           // 786432
  if (idx >= 786432) return;
  int o = idx / 1536, c = idx % 1536;
  int w = c / 512, i = c % 512;
  w2[idx] = f2bf(cw[o * 1536 + i * 3 + w]);
}

__global__ void k_embed(const int* __restrict__ sents, const int* __restrict__ masks,
                        const float* __restrict__ wemb, const float* __restrict__ memb,
                        s16* __restrict__ x0) {
  int idx = blockIdx.x * 256 + threadIdx.x;           // 128*100*352
  if (idx >= BB * TT * 352) return;
  int c = idx % 352, bt = idx / 352;
  float v;
  if (c < 300)      v = wemb[(size_t)sents[bt] * 300 + c];
  else if (c < 350) v = memb[masks[bt] * 50 + (c - 300)];
  else              v = 0.f;
  x0[idx] = f2bf(v);
}

__global__ void k_zero16(uint4* __restrict__ p, int n16) {
  int idx = blockIdx.x * 256 + threadIdx.x;
  if (idx < n16) p[idx] = make_uint4(0u, 0u, 0u, 0u);
}

// ---------------- GEMM: C[M,N](bf16) = A[M,K](bf16) * B[N,K](bf16)^T ----------------
// 128x128 tile, 4 waves (2x2 of 64x64), BK=32, reg-staged LDS.
__global__ __launch_bounds__(256) void k_gemm(const s16* __restrict__ A, const s16* __restrict__ Bm,
                                              s16* __restrict__ C, int K, int ldA, int ldB, int ldC,
                                              const float* __restrict__ bias, int relu) {
  __shared__ s16 As[128 * 32];
  __shared__ s16 Bs[128 * 32];
  const int t = threadIdx.x, w = t >> 6, l = t & 63;
  const size_t m0 = (size_t)blockIdx.x * 128, n0 = (size_t)blockIdx.y * 128;
  f32x4 zero = {0.f, 0.f, 0.f, 0.f};
  f32x4 acc[4][4];
#pragma unroll
  for (int i = 0; i < 4; ++i)
#pragma unroll
    for (int j = 0; j < 4; ++j) acc[i][j] = zero;

  for (int kb = 0; kb < K; kb += 32) {
    __syncthreads();
    {
      const s16* gA = A + (m0 + (t >> 1)) * (size_t)ldA + kb + 16 * (t & 1);
      *(s16x8*)&As[(t >> 1) * 32 + 16 * (t & 1)]     = *(const s16x8*)gA;
      *(s16x8*)&As[(t >> 1) * 32 + 16 * (t & 1) + 8] = *(const s16x8*)(gA + 8);
      const s16* gB = Bm + (n0 + (t >> 1)) * (size_t)ldB + kb + 16 * (t & 1);
      *(s16x8*)&Bs[(t >> 1) * 32 + 16 * (t & 1)]     = *(const s16x8*)gB;
      *(s16x8*)&Bs[(t >> 1) * 32 + 16 * (t & 1) + 8] = *(const s16x8*)(gB + 8);
    }
    __syncthreads();
    s16x8 a[4], b[4];
#pragma unroll
    for (int i = 0; i < 4; ++i)
      a[i] = *(const s16x8*)&As[(64 * (w >> 1) + 16 * i + (l & 15)) * 32 + 8 * (l >> 4)];
#pragma unroll
    for (int j = 0; j < 4; ++j)
      b[j] = *(const s16x8*)&Bs[(64 * (w & 1) + 16 * j + (l & 15)) * 32 + 8 * (l >> 4)];
#pragma unroll
    for (int i = 0; i < 4; ++i)
#pragma unroll
      for (int j = 0; j < 4; ++j)
        acc[i][j] = __builtin_amdgcn_mfma_f32_16x16x32_bf16(a[i], b[j], acc[i][j], 0, 0, 0);
  }
#pragma unroll
  for (int i = 0; i < 4; ++i)
#pragma unroll
    for (int j = 0; j < 4; ++j)
#pragma unroll
      for (int r = 0; r < 4; ++r) {
        size_t row = m0 + 64 * (w >> 1) + 16 * i + 4 * (l >> 4) + r;
        size_t col = n0 + 64 * (w & 1) + 16 * j + (l & 15);
        float v = acc[i][j][r];
        if (bias) v += bias[col];
        if (relu) v = fmaxf(v, 0.f);
        C[row * (size_t)ldC + col] = f2bf(v);
      }
}

// ---------------- persistent GRU (one layer, both dirs) ----------------
// grid (8,2): blockIdx.x = 16-row group, blockIdx.y = dir (0 fwd, 1 bwd).
// 512 threads = 8 waves; wave w owns gh columns [96w, 96w+96) with whh
// B-frags in 192 VGPRs. h state in LDS: hf (f32, exact) + hb (bf16 A-operand).
__global__ __launch_bounds__(512) void k_gru(
    const s16* __restrict__ gi_f, const s16* __restrict__ gi_b,
    const s16* __restrict__ wf_f, const s16* __restrict__ wf_b,
    const float* __restrict__ bih_f, const float* __restrict__ bhh_f,
    const float* __restrict__ bih_b, const float* __restrict__ bhh_b,
    const int* __restrict__ lens, s16* __restrict__ out) {
  const int g = blockIdx.x;
  const int dir = blockIdx.y;
  const int tid = threadIdx.x, wid = tid >> 6, l = tid & 63;
  const s16* gi = dir ? gi_b : gi_f;
  const s16* wf = dir ? wf_b : wf_f;
  const float* bih = dir ? bih_b : bih_f;
  const float* bhh = dir ? bhh_b : bhh_f;
  const int col_off = dir ? 256 : 0;
  const int b0 = g * 16;

  __shared__ float gh2[768 * 20];   // [col][20], rows in [0,16)
  __shared__ float hf[16 * 256];
  __shared__ s16 hb[16 * 264];      // +8 pad
  __shared__ float s_bih[768], s_bhh[768];
  __shared__ int s_len[16];

  s16x8 wv[48];
#pragma unroll
  for (int f = 0; f < 48; ++f)
    wv[f] = *(const s16x8*)&wf[((size_t)(wid * 48 + f)) * 512 + l * 8];

  for (int i = tid; i < 16 * 256; i += 512) hf[i] = 0.f;
  for (int i = tid; i < 16 * 264; i += 512) hb[i] = 0;
  for (int i = tid; i < 768; i += 512) { s_bih[i] = bih[i]; s_bhh[i] = bhh[i]; }
  if (tid < 16) s_len[tid] = lens[b0 + tid];
  __syncthreads();

  const int smax = s_len[0];   // lens sorted descending

  for (int s = 0; s < smax; ++s) {
    f32x4 zero = {0.f, 0.f, 0.f, 0.f};
    f32x4 acc[6];
#pragma unroll
    for (int nt = 0; nt < 6; ++nt) acc[nt] = zero;
#pragma unroll
    for (int kt = 0; kt < 8; ++kt) {
      s16x8 a = *(const s16x8*)&hb[(l & 15) * 264 + 32 * kt + 8 * (l >> 4)];
#pragma unroll
      for (int nt = 0; nt < 6; ++nt)
        acc[nt] = __builtin_amdgcn_mfma_f32_16x16x32_bf16(a, wv[nt * 8 + kt], acc[nt], 0, 0, 0);
    }
#pragma unroll
    for (int nt = 0; nt < 6; ++nt) {
      int col = 96 * wid + 16 * nt + (l & 15);
      *(f32x4*)&gh2[col * 20 + 4 * (l >> 4)] = acc[nt];
    }
    __syncthreads();
    // gate phase: 4096 (row,j) dims over 512 threads
    for (int i = 0; i < 8; ++i) {
      int d = tid + 512 * i;
      int row = d >> 8, j = d & 255;
      int len = s_len[row];
      if (s < len) {
        int b = b0 + row;
        int p = dir ? (len - 1 - s) : s;
        const s16* gp = gi + (size_t)(b * TT + p) * 768;
        float gir = bf2f(gp[j]) + s_bih[j];
        float giz = bf2f(gp[256 + j]) + s_bih[256 + j];
        float gin = bf2f(gp[512 + j]) + s_bih[512 + j];
        float ghr = gh2[j * 20 + row] + s_bhh[j];
        float ghz = gh2[(256 + j) * 20 + row] + s_bhh[256 + j];
        float ghn = gh2[(512 + j) * 20 + row] + s_bhh[512 + j];
        float r = sigf(gir + ghr);
        float z = sigf(giz + ghz);
        float n = tanhfast(gin + r * ghn);
        float ho = hf[row * 256 + j];
        float hn = (1.f - z) * n + z * ho;
        hf[row * 256 + j] = hn;
        hb[row * 264 + j] = f2bf(hn);
        out[(size_t)(b * TT + p) * 512 + col_off + j] = f2bf(hn);
      }
    }
    __syncthreads();
  }
}

// ---------------- im2col for conv (k=3, pad 1) ----------------
__global__ void k_im2col(const s16* __restrict__ x2, s16* __restrict__ A2) {
  int idx = blockIdx.x * 256 + threadIdx.x;           // 12800*1536/8
  if (idx >= 2457600) return;
  size_t e = (size_t)idx * 8;
  int bt = (int)(e / 1536), c = (int)(e % 1536);
  int w = c / 512, i = c % 512;
  int b = bt / TT, t = bt % TT;
  int ts = t + w - 1;
  s16x8 v;
  if (ts >= 0 && ts < TT) v = *(const s16x8*)&x2[(size_t)(b * TT + ts) * 512 + i];
  else { s16x8 z = {0,0,0,0,0,0,0,0}; v = z; }
  *(s16x8*)&A2[e] = v;
}

// ---------------- small epilogue kernels ----------------
__global__ void k_avg(const s16* __restrict__ ctx, const int* __restrict__ masks,
                      float* __restrict__ avg) {
  int b = blockIdx.x, t = threadIdx.x;  // 256
  float a0 = 0, a1 = 0, ms = 0;
  for (int tt = 0; tt < TT; ++tt) {
    float mf = (float)masks[b * TT + tt];
    ms += mf;
    if (mf != 0.f) {
      a0 += mf * bf2f(ctx[(size_t)(b * TT + tt) * 512 + t]);
      a1 += mf * bf2f(ctx[(size_t)(b * TT + tt) * 512 + 256 + t]);
    }
  }
  avg[b * 512 + t] = a0 / ms;
  avg[b * 512 + 256 + t] = a1 / ms;
}

__global__ void k_tri(const s16* __restrict__ ctx, const float* __restrict__ avg,
                      const float* __restrict__ triw, const float* __restrict__ trib,
                      float* __restrict__ tri) {
  int gw = (blockIdx.x * 256 + threadIdx.x) >> 6;
  int l = threadIdx.x & 63;
  if (gw >= BB * TT) return;
  int b = gw / TT;
  float a0 = 0, a1 = 0;
  for (int it = 0; it < 16; ++it) {
    int k = l + 64 * it;
    float v = (k < 512) ? bf2f(ctx[(size_t)gw * 512 + k]) : avg[b * 512 + k - 512];
    a0 += v * triw[k];
    a1 += v * triw[1024 + k];
  }
  for (int off = 32; off; off >>= 1) {
    a0 += __shfl_down(a0, off, 64);
    a1 += __shfl_down(a1, off, 64);
  }
  if (l == 0) {
    tri[gw * 2]     = a0 + trib[0];
    tri[gw * 2 + 1] = a1 + trib[1];
  }
}

__global__ void k_crf(const float* __restrict__ tri, const int* __restrict__ lens,
                      const float* __restrict__ trans, float* __restrict__ alphas,
                      float* __restrict__ sp, float* __restrict__ sp_sum) {
  int b = threadIdx.x;  // 128 threads, 1 block
  int L = lens[b];
  float t00 = trans[0], t01 = trans[1], t10 = trans[2], t11 = trans[3];
  const float* f = tri + b * 2 * TT;
  float* al = alphas + b * 2 * TT;
  float a0 = f[0], a1 = f[1];
  al[0] = a0; al[1] = a1;
  for (int t = 1; t < TT; ++t) {
    if (t < L) {
      float n0 = lse2(a0 + t00, a1 + t10) + f[2 * t];
      float n1 = lse2(a0 + t01, a1 + t11) + f[2 * t + 1];
      a0 = n0; a1 = n1;
    }
    al[2 * t] = a0; al[2 * t + 1] = a1;
  }
  float logZ = lse2(a0, a1);
  float b0 = 0.f, b1 = 0.f, ssum = 0.f;
  {
    float v = (TT - 1 < L) ? expf(al[2 * (TT - 1) + 1] - logZ) : 0.f;
    sp[b * TT + TT - 1] = v; ssum += v;
  }
  for (int t = TT - 2; t >= 0; --t) {
    float fn0 = f[2 * (t + 1)], fn1 = f[2 * (t + 1) + 1];
    float c0 = lse2(t00 + fn0 + b0, t01 + fn1 + b1);
    float c1 = lse2(t10 + fn0 + b0, t11 + fn1 + b1);
    if (t >= L - 1) { b0 = 0.f; b1 = 0.f; } else { b0 = c0; b1 = c1; }
    float v = (t < L) ? expf(al[2 * t + 1] + b1 - logZ) : 0.f;
    sp[b * TT + t] = v; ssum += v;
  }
  sp_sum[b] = ssum;
}

__global__ void k_sentv(const s16* __restrict__ ctx, const float* __restrict__ sp,
                        float* __restrict__ sv) {
  int b = blockIdx.x, t = threadIdx.x;  // 256
  float a0 = 0, a1 = 0;
  for (int tt = 0; tt < TT; ++tt) {
    float w = sp[b * TT + tt];
    if (w != 0.f) {
      a0 += w * bf2f(ctx[(size_t)(b * TT + tt) * 512 + t]);
      a1 += w * bf2f(ctx[(size_t)(b * TT + tt) * 512 + 256 + t]);
    }
  }
  sv[b * 512 + t] = a0;
  sv[b * 512 + 256 + t] = a1;
}

__global__ void k_final(const float* __restrict__ sv, const float* __restrict__ sp_sum,
                        const int* __restrict__ labels, const float* __restrict__ labw,
                        const float* __restrict__ labb, const float* __restrict__ trans,
                        float* __restrict__ out) {
  __shared__ float red[128];
  int b = threadIdx.x;  // 128
  float g = sp_sum[b] * 0.5f;
  g = fminf(fmaxf(g, 1e-4f), 1e5f);
  float s[3];
  for (int c = 0; c < 3; ++c) {
    float a = 0.f;
    for (int h = 0; h < 512; ++h) a += sv[b * 512 + h] * labw[c * 512 + h];
    s[c] = a / g + labb[c];
  }
  float m = fmaxf(s[0], fmaxf(s[1], s[2]));
  float lse = m + logf(expf(s[0] - m) + expf(s[1] - m) + expf(s[2] - m));
  red[b] = -(s[labels[b]] - lse);
  __syncthreads();
  if (b == 0) {
    float acc = 0.f, sn = 0.f;
    for (int i = 0; i < 128; ++i) { acc += red[i]; sn += sp_sum[i]; }
    float pena = fmaxf(trans[2] - trans[0], 0.f) + fmaxf(trans[1] - trans[3], 0.f);
    out[0] = acc / 128.f;
    out[1] = 0.1f * pena + 0.1f * (sn / 128.f);
  }
}

// ---------------- launcher ----------------
extern "C" void kernel_launch(void* const* d_in, const int* in_sizes, int n_in,
                              void* d_out, int out_size, void* d_ws, size_t ws_size,
                              hipStream_t stream) {
  const int*   sents  = (const int*)d_in[0];
  const int*   lens   = (const int*)d_in[1];
  const int*   masks  = (const int*)d_in[2];
  const int*   labels = (const int*)d_in[3];
  const float* wemb   = (const float*)d_in[4];
  const float* memb   = (const float*)d_in[5];
  const float* wih0f = (const float*)d_in[6],  *whh0f = (const float*)d_in[7];
  const float* bih0f = (const float*)d_in[8],  *bhh0f = (const float*)d_in[9];
  const float* wih0b = (const float*)d_in[10], *whh0b = (const float*)d_in[11];
  const float* bih0b = (const float*)d_in[12], *bhh0b = (const float*)d_in[13];
  const float* wih1f = (const float*)d_in[14], *whh1f = (const float*)d_in[15];
  const float* bih1f = (const float*)d_in[16], *bhh1f = (const float*)d_in[17];
  const float* wih1b = (const float*)d_in[18], *whh1b = (const float*)d_in[19];
  const float* bih1b = (const float*)d_in[20], *bhh1b = (const float*)d_in[21];
  const float* convw = (const float*)d_in[22], *convb = (const float*)d_in[23];
  const float* triw  = (const float*)d_in[24], *trib  = (const float*)d_in[25];
  const float* trans = (const float*)d_in[26];
  const float* labw  = (const float*)d_in[27], *labb  = (const float*)d_in[28];
  float* out = (float*)d_out;
  char* ws = (char*)d_ws;

  s16* x0    = (s16*)(ws + 0);
  s16* cwih0f = (s16*)(ws + 9011200);
  s16* cwih0b = (s16*)(ws + 9551872);
  s16* cwih1f = (s16*)(ws + 10092544);
  s16* cwih1b = (s16*)(ws + 10878976);
  s16* wf0f  = (s16*)(ws + 11665408);
  s16* wf0b  = (s16*)(ws + 12058624);
  s16* wf1f  = (s16*)(ws + 12451840);
  s16* wf1b  = (s16*)(ws + 12845056);
  s16* w2    = (s16*)(ws + 13238272);
  s16* giF   = (s16*)(ws + 14811136);
  s16* giB   = (s16*)(ws + 34471936);
  s16* x1    = (s16*)(ws + 54132736);
  s16* x2    = (s16*)(ws + 67239936);
  s16* A2    = giF;            // alias: gi dead after gru1
  s16* ctx   = x1;             // alias: x1 dead after gi1 GEMMs
  float* avg   = (float*)(ws + 80347136);
  float* tri   = (float*)(ws + 80609280);
  float* alphas= (float*)(ws + 80711680);
  float* sp    = (float*)(ws + 80814080);
  float* spsum = (float*)(ws + 80865280);
  float* sentv = (float*)(ws + 80865792);

  // prep
  k_cvtpad<<<1056, 256, 0, stream>>>(wih0f, cwih0f);
  k_cvtpad<<<1056, 256, 0, stream>>>(wih0b, cwih0b);
  k_cvt<<<1536, 256, 0, stream>>>(wih1f, cwih1f, 393216);
  k_cvt<<<1536, 256, 0, stream>>>(wih1b, cwih1b, 393216);
  k_wfrag<<<768, 256, 0, stream>>>(whh0f, wf0f);
  k_wfrag<<<768, 256, 0, stream>>>(whh0b, wf0b);
  k_wfrag<<<768, 256, 0, stream>>>(whh1f, wf1f);
  k_wfrag<<<768, 256, 0, stream>>>(whh1b, wf1b);
  k_w2<<<3072, 256, 0, stream>>>(convw, w2);
  k_embed<<<17600, 256, 0, stream>>>(sents, masks, wemb, memb, x0);
  k_zero16<<<3200, 256, 0, stream>>>((uint4*)x1, 819200);
  k_zero16<<<3200, 256, 0, stream>>>((uint4*)x2, 819200);

  // layer 0
  k_gemm<<<dim3(100, 6), 256, 0, stream>>>(x0, cwih0f, giF, 352, 352, 352, 768, nullptr, 0);
  k_gemm<<<dim3(100, 6), 256, 0, stream>>>(x0, cwih0b, giB, 352, 352, 352, 768, nullptr, 0);
  k_gru<<<dim3(8, 2), 512, 0, stream>>>(giF, giB, wf0f, wf0b, bih0f, bhh0f, bih0b, bhh0b, lens, x1);

  // layer 1
  k_gemm<<<dim3(100, 6), 256, 0, stream>>>(x1, cwih1f, giF, 512, 512, 512, 768, nullptr, 0);
  k_gemm<<<dim3(100, 6), 256, 0, stream>>>(x1, cwih1b, giB, 512, 512, 512, 768, nullptr, 0);
  k_gru<<<dim3(8, 2), 512, 0, stream>>>(giF, giB, wf1f, wf1b, bih1f, bhh1f, bih1b, bhh1b, lens, x2);

  // conv + epilogue
  k_im2col<<<9600, 256, 0, stream>>>(x2, A2);
  k_gemm<<<dim3(100, 4), 256, 0, stream>>>(A2, w2, ctx, 1536, 1536, 1536, 512, convb, 1);
  k_avg<<<128, 256, 0, stream>>>(ctx, masks, avg);
  k_tri<<<3200, 256, 0, stream>>>(ctx, avg, triw, trib, tri);
  k_crf<<<1, 128, 0, stream>>>(tri, lens, trans, alphas, sp, spsum);
  k_sentv<<<128, 256, 0, stream>>>(ctx, sp, sentv);
  k_final<<<1, 128, 0, stream>>>(sentv, spsum, labels, labw, labb, trans, out);
}

// Round 5
// 1142.831 us; speedup vs baseline: 2.3860x; 2.3860x over previous
//
#include <hip/hip_runtime.h>
#include <hip/hip_bf16.h>
#include <stdint.h>

// AspectSent forward on MI355X.
// Pipeline: embed -> [gi GEMM(+bih) -> persistent GRU]x2 layers (f+b dirs) ->
// im2col -> conv GEMM(+relu) -> avg -> tri -> CRF -> sent_v -> loss.
// All matmuls bf16 MFMA 16x16x32, f32 accumulate.
// GRU: 32 blocks (16 groups x 8 rows x 2 dirs), 8 waves; whh VGPR-resident
// (48 B-frags = 192 VGPR/wave). HARD CAP: 512-thr block => 2 waves/SIMD =>
// <=256 VGPR/wave (VRF 512/SIMD). Design fits ~250: gate = 2 (row,j-pair)
// items/thread, packed u32 gi prefetch, bih folded into gi GEMM, h in regs.

#define TT 100
#define BB 128

typedef short s16;
typedef unsigned int u32;
typedef __attribute__((ext_vector_type(8))) short s16x8;
typedef __attribute__((ext_vector_type(4))) float f32x4;
typedef __attribute__((ext_vector_type(2))) float f32x2;

__device__ __forceinline__ float bf2f(s16 s) {
  return __uint_as_float(((unsigned)(unsigned short)s) << 16);
}
__device__ __forceinline__ s16 f2bf(float f) {
  __hip_bfloat16 h = __float2bfloat16(f);
  return *(s16*)&h;
}
__device__ __forceinline__ float sigf(float x) { return 1.f / (1.f + __expf(-x)); }
__device__ __forceinline__ float tanhfast(float x) { return 2.f / (1.f + __expf(-2.f * x)) - 1.f; }
__device__ __forceinline__ float lse2(float a, float b) {
  float m = fmaxf(a, b);
  return m + logf(expf(a - m) + expf(b - m));
}

// ---------------- prep kernels ----------------

// f32 (768x350) -> bf16 (768x352), zero-pad last 2 cols
__global__ void k_cvtpad(const float* __restrict__ src, s16* __restrict__ dst) {
  int idx = blockIdx.x * 256 + threadIdx.x;           // 768*352
  if (idx >= 768 * 352) return;
  int n = idx / 352, k = idx % 352;
  dst[idx] = (k < 350) ? f2bf(src[n * 350 + k]) : (s16)0;
}

__global__ void k_cvt(const float* __restrict__ src, s16* __restrict__ dst, int n) {
  int idx = blockIdx.x * 256 + threadIdx.x;
  if (idx < n) dst[idx] = f2bf(src[idx]);
}

// whh (768x256 f32) -> MFMA B-fragment layout bf16.
// wf[((w*48 + f)*64 + l)*8 + i] = whh[col*256 + k],
//   f = nt*8+kt, col = 96w+16nt+(l&15), k = 32kt+8*(l>>4)+i
__global__ void k_wfrag(const float* __restrict__ whh, s16* __restrict__ wf) {
  int tid = blockIdx.x * 256 + threadIdx.x;           // 196608
  if (tid >= 196608) return;
  int w = tid / 24576, rem = tid % 24576;
  int f = rem / 512, rem2 = rem % 512;
  int l = rem2 / 8, i = rem2 % 8;
  int nt = f / 8, kt = f % 8;
  int col = 96 * w + 16 * nt + (l & 15);
  int k = 32 * kt + 8 * (l >> 4) + i;
  wf[tid] = f2bf(whh[col * 256 + k]);
}

// conv_w (512,512,3) -> w2 bf16 [512][1536], w2[o][w*512+i] = conv_w[o,i,w]
__global__ void k_w2(const float* __restrict__ cw, s16* __restrict__ w2) {
  int idx = blockIdx.x * 256 + threadIdx.x;           // 786432
  if (idx >= 786432) return;
  int o = idx / 1536, c = idx % 1536;
  int w = c / 512, i = c % 512;
  w2[idx] = f2bf(cw[o * 1536 + i * 3 + w]);
}

__global__ void k_embed(const int* __restrict__ sents, const int* __restrict__ masks,
                        const float* __restrict__ wemb, const float* __restrict__ memb,
                        s16* __restrict__ x0) {
  int idx = blockIdx.x * 256 + threadIdx.x;           // 128*100*352
  if (idx >= BB * TT * 352) return;
  int c = idx % 352, bt = idx / 352;
  float v;
  if (c < 300)      v = wemb[(size_t)sents[bt] * 300 + c];
  else if (c < 350) v = memb[masks[bt] * 50 + (c - 300)];
  else              v = 0.f;
  x0[idx] = f2bf(v);
}

__global__ void k_zero16(uint4* __restrict__ p, int n16) {
  int idx = blockIdx.x * 256 + threadIdx.x;
  if (idx < n16) p[idx] = make_uint4(0u, 0u, 0u, 0u);
}

// ---------------- GEMM: C[M,N](bf16) = A[M,K](bf16) * B[N,K](bf16)^T ----------------
// 128x128 tile, 4 waves (2x2 of 64x64), BK=32, reg-staged LDS.
__global__ __launch_bounds__(256) void k_gemm(const s16* __restrict__ A, const s16* __restrict__ Bm,
                                              s16* __restrict__ C, int K, int ldA, int ldB, int ldC,
                                              const float* __restrict__ bias, int relu) {
  __shared__ s16 As[128 * 32];
  __shared__ s16 Bs[128 * 32];
  const int t = threadIdx.x, w = t >> 6, l = t & 63;
  const size_t m0 = (size_t)blockIdx.x * 128, n0 = (size_t)blockIdx.y * 128;
  f32x4 zero = {0.f, 0.f, 0.f, 0.f};
  f32x4 acc[4][4];
#pragma unroll
  for (int i = 0; i < 4; ++i)
#pragma unroll
    for (int j = 0; j < 4; ++j) acc[i][j] = zero;

  for (int kb = 0; kb < K; kb += 32) {
    __syncthreads();
    {
      const s16* gA = A + (m0 + (t >> 1)) * (size_t)ldA + kb + 16 * (t & 1);
      *(s16x8*)&As[(t >> 1) * 32 + 16 * (t & 1)]     = *(const s16x8*)gA;
      *(s16x8*)&As[(t >> 1) * 32 + 16 * (t & 1) + 8] = *(const s16x8*)(gA + 8);
      const s16* gB = Bm + (n0 + (t >> 1)) * (size_t)ldB + kb + 16 * (t & 1);
      *(s16x8*)&Bs[(t >> 1) * 32 + 16 * (t & 1)]     = *(const s16x8*)gB;
      *(s16x8*)&Bs[(t >> 1) * 32 + 16 * (t & 1) + 8] = *(const s16x8*)(gB + 8);
    }
    __syncthreads();
    s16x8 a[4], b[4];
#pragma unroll
    for (int i = 0; i < 4; ++i)
      a[i] = *(const s16x8*)&As[(64 * (w >> 1) + 16 * i + (l & 15)) * 32 + 8 * (l >> 4)];
#pragma unroll
    for (int j = 0; j < 4; ++j)
      b[j] = *(const s16x8*)&Bs[(64 * (w & 1) + 16 * j + (l & 15)) * 32 + 8 * (l >> 4)];
#pragma unroll
    for (int i = 0; i < 4; ++i)
#pragma unroll
      for (int j = 0; j < 4; ++j)
        acc[i][j] = __builtin_amdgcn_mfma_f32_16x16x32_bf16(a[i], b[j], acc[i][j], 0, 0, 0);
  }
#pragma unroll
  for (int i = 0; i < 4; ++i)
#pragma unroll
    for (int j = 0; j < 4; ++j)
#pragma unroll
      for (int r = 0; r < 4; ++r) {
        size_t row = m0 + 64 * (w >> 1) + 16 * i + 4 * (l >> 4) + r;
        size_t col = n0 + 64 * (w & 1) + 16 * j + (l & 15);
        float v = acc[i][j][r];
        if (bias) v += bias[col];
        if (relu) v = fmaxf(v, 0.f);
        C[row * (size_t)ldC + col] = f2bf(v);
      }
}

// ---------------- persistent GRU (one layer, both dirs) ----------------
// grid (16,2): blockIdx.x = 8-row group, blockIdx.y = dir (0 fwd, 1 bwd).
// 512 threads = 8 waves; wave w owns gh columns [96w, 96w+96), whh B-frags
// in 192 VGPRs. Gate: thread handles rows {r0, r0+4} x j-pair {j0, j0+1}.
// gi comes with bih pre-added (folded into gi GEMM bias).
__global__ __launch_bounds__(512, 2) void k_gru(
    const s16* __restrict__ gi_f, const s16* __restrict__ gi_b,
    const s16* __restrict__ wf_f, const s16* __restrict__ wf_b,
    const float* __restrict__ bhh_f, const float* __restrict__ bhh_b,
    const int* __restrict__ lens, s16* __restrict__ out) {
  const int g = blockIdx.x;
  const int dir = blockIdx.y;
  const int tid = threadIdx.x, wid = tid >> 6, l = tid & 63;
  const s16* gi = dir ? gi_b : gi_f;
  const s16* wf = dir ? wf_b : wf_f;
  const float* bhh = dir ? bhh_b : bhh_f;
  const int col_off = dir ? 256 : 0;
  const int b0 = g * 8;

  __shared__ __align__(16) float gh2[16 * 772];  // rows 8..15 written, unused
  __shared__ __align__(16) s16 hb[16 * 264];     // rows 8..15 stay zero
  __shared__ float s_bhh[768];
  __shared__ int s_len[8];

  // whh B-fragments, VGPR-resident (192 VGPRs)
  s16x8 wv[48];
#pragma unroll
  for (int f = 0; f < 48; ++f)
    wv[f] = *(const s16x8*)&wf[((size_t)(wid * 48 + f)) * 512 + l * 8];

  for (int i = tid; i < 16 * 264; i += 512) hb[i] = 0;
  for (int i = tid; i < 768; i += 512) s_bhh[i] = bhh[i];
  if (tid < 8) s_len[tid] = lens[b0 + tid];
  __syncthreads();

  const int smax = s_len[0];   // lens sorted descending

  // gate geometry: j-pair j0 fixed; rows r0 and r0+4
  const int j0 = (tid & 127) * 2;
  const int r0 = tid >> 7;                 // 0..3
  const int len0 = s_len[r0];
  const int len1 = s_len[r0 + 4];
  const float bhr0 = s_bhh[j0],       bhr1 = s_bhh[j0 + 1];
  const float bhz0 = s_bhh[256 + j0], bhz1 = s_bhh[257 + j0];
  const float bhn0 = s_bhh[512 + j0], bhn1 = s_bhh[513 + j0];
  float hp00 = 0.f, hp01 = 0.f, hp10 = 0.f, hp11 = 0.f;

  for (int s = 0; s < smax; ++s) {
    // ---- prefetch gi (u32 = 2 bf16) for this step; hidden under MFMAs ----
    u32 q00 = 0, q01 = 0, q02 = 0, q10 = 0, q11 = 0, q12 = 0;
    int p0 = 0, p1 = 0;
    if (s < len0) {
      p0 = dir ? (len0 - 1 - s) : s;
      const s16* gp = gi + ((size_t)(b0 + r0) * TT + p0) * 768 + j0;
      q00 = *(const u32*)gp; q01 = *(const u32*)(gp + 256); q02 = *(const u32*)(gp + 512);
    }
    if (s < len1) {
      p1 = dir ? (len1 - 1 - s) : s;
      const s16* gp = gi + ((size_t)(b0 + r0 + 4) * TT + p1) * 768 + j0;
      q10 = *(const u32*)gp; q11 = *(const u32*)(gp + 256); q12 = *(const u32*)(gp + 512);
    }

    // ---- MFMA phase: gh = hb @ whh^T ----
    f32x4 zero = {0.f, 0.f, 0.f, 0.f};
    f32x4 acc[6];
#pragma unroll
    for (int nt = 0; nt < 6; ++nt) acc[nt] = zero;
#pragma unroll
    for (int kt = 0; kt < 8; ++kt) {
      s16x8 a = *(const s16x8*)&hb[(l & 15) * 264 + 32 * kt + 8 * (l >> 4)];
#pragma unroll
      for (int nt = 0; nt < 6; ++nt)
        acc[nt] = __builtin_amdgcn_mfma_f32_16x16x32_bf16(a, wv[nt * 8 + kt], acc[nt], 0, 0, 0);
    }
#pragma unroll
    for (int nt = 0; nt < 6; ++nt) {
      int col = 96 * wid + 16 * nt + (l & 15);
#pragma unroll
      for (int r = 0; r < 4; ++r)
        gh2[(4 * (l >> 4) + r) * 772 + col] = acc[nt][r];
    }
    __syncthreads();

    // ---- gate phase: 2 rows x j-pair ----
    if (s < len0) {
      f32x2 gr = *(const f32x2*)&gh2[r0 * 772 + j0];
      f32x2 gz = *(const f32x2*)&gh2[r0 * 772 + 256 + j0];
      f32x2 gn = *(const f32x2*)&gh2[r0 * 772 + 512 + j0];
      float rr0 = sigf(bf2f((s16)(q00 & 0xffff)) + gr[0] + bhr0);
      float rr1 = sigf(bf2f((s16)(q00 >> 16))    + gr[1] + bhr1);
      float zz0 = sigf(bf2f((s16)(q01 & 0xffff)) + gz[0] + bhz0);
      float zz1 = sigf(bf2f((s16)(q01 >> 16))    + gz[1] + bhz1);
      float nn0 = tanhfast(bf2f((s16)(q02 & 0xffff)) + rr0 * (gn[0] + bhn0));
      float nn1 = tanhfast(bf2f((s16)(q02 >> 16))    + rr1 * (gn[1] + bhn1));
      hp00 = (1.f - zz0) * nn0 + zz0 * hp00;
      hp01 = (1.f - zz1) * nn1 + zz1 * hp01;
      u32 pk = (u32)(unsigned short)f2bf(hp00) | ((u32)(unsigned short)f2bf(hp01) << 16);
      *(u32*)&hb[r0 * 264 + j0] = pk;
      *(u32*)&out[((size_t)(b0 + r0) * TT + p0) * 512 + col_off + j0] = pk;
    }
    if (s < len1) {
      int row = r0 + 4;
      f32x2 gr = *(const f32x2*)&gh2[row * 772 + j0];
      f32x2 gz = *(const f32x2*)&gh2[row * 772 + 256 + j0];
      f32x2 gn = *(const f32x2*)&gh2[row * 772 + 512 + j0];
      float rr0 = sigf(bf2f((s16)(q10 & 0xffff)) + gr[0] + bhr0);
      float rr1 = sigf(bf2f((s16)(q10 >> 16))    + gr[1] + bhr1);
      float zz0 = sigf(bf2f((s16)(q11 & 0xffff)) + gz[0] + bhz0);
      float zz1 = sigf(bf2f((s16)(q11 >> 16))    + gz[1] + bhz1);
      float nn0 = tanhfast(bf2f((s16)(q12 & 0xffff)) + rr0 * (gn[0] + bhn0));
      float nn1 = tanhfast(bf2f((s16)(q12 >> 16))    + rr1 * (gn[1] + bhn1));
      hp10 = (1.f - zz0) * nn0 + zz0 * hp10;
      hp11 = (1.f - zz1) * nn1 + zz1 * hp11;
      u32 pk = (u32)(unsigned short)f2bf(hp10) | ((u32)(unsigned short)f2bf(hp11) << 16);
      *(u32*)&hb[row * 264 + j0] = pk;
      *(u32*)&out[((size_t)(b0 + row) * TT + p1) * 512 + col_off + j0] = pk;
    }
    __syncthreads();
  }
}

// ---------------- im2col for conv (k=3, pad 1) ----------------
__global__ void k_im2col(const s16* __restrict__ x2, s16* __restrict__ A2) {
  int idx = blockIdx.x * 256 + threadIdx.x;           // 12800*1536/8
  if (idx >= 2457600) return;
  size_t e = (size_t)idx * 8;
  int bt = (int)(e / 1536), c = (int)(e % 1536);
  int w = c / 512, i = c % 512;
  int b = bt / TT, t = bt % TT;
  int ts = t + w - 1;
  s16x8 v;
  if (ts >= 0 && ts < TT) v = *(const s16x8*)&x2[(size_t)(b * TT + ts) * 512 + i];
  else { s16x8 z = {0,0,0,0,0,0,0,0}; v = z; }
  *(s16x8*)&A2[e] = v;
}

// ---------------- small epilogue kernels ----------------
__global__ void k_avg(const s16* __restrict__ ctx, const int* __restrict__ masks,
                      float* __restrict__ avg) {
  int b = blockIdx.x, t = threadIdx.x;  // 256
  float a0 = 0, a1 = 0, ms = 0;
  for (int tt = 0; tt < TT; ++tt) {
    float mf = (float)masks[b * TT + tt];
    ms += mf;
    if (mf != 0.f) {
      a0 += mf * bf2f(ctx[(size_t)(b * TT + tt) * 512 + t]);
      a1 += mf * bf2f(ctx[(size_t)(b * TT + tt) * 512 + 256 + t]);
    }
  }
  avg[b * 512 + t] = a0 / ms;
  avg[b * 512 + 256 + t] = a1 / ms;
}

__global__ void k_tri(const s16* __restrict__ ctx, const float* __restrict__ avg,
                      const float* __restrict__ triw, const float* __restrict__ trib,
                      float* __restrict__ tri) {
  int gw = (blockIdx.x * 256 + threadIdx.x) >> 6;
  int l = threadIdx.x & 63;
  if (gw >= BB * TT) return;
  int b = gw / TT;
  float a0 = 0, a1 = 0;
  for (int it = 0; it < 16; ++it) {
    int k = l + 64 * it;
    float v = (k < 512) ? bf2f(ctx[(size_t)gw * 512 + k]) : avg[b * 512 + k - 512];
    a0 += v * triw[k];
    a1 += v * triw[1024 + k];
  }
  for (int off = 32; off; off >>= 1) {
    a0 += __shfl_down(a0, off, 64);
    a1 += __shfl_down(a1, off, 64);
  }
  if (l == 0) {
    tri[gw * 2]     = a0 + trib[0];
    tri[gw * 2 + 1] = a1 + trib[1];
  }
}

__global__ void k_crf(const float* __restrict__ tri, const int* __restrict__ lens,
                      const float* __restrict__ trans, float* __restrict__ alphas,
                      float* __restrict__ sp, float* __restrict__ sp_sum) {
  int b = threadIdx.x;  // 128 threads, 1 block
  int L = lens[b];
  float t00 = trans[0], t01 = trans[1], t10 = trans[2], t11 = trans[3];
  const float* f = tri + b * 2 * TT;
  float* al = alphas + b * 2 * TT;
  float a0 = f[0], a1 = f[1];
  al[0] = a0; al[1] = a1;
  for (int t = 1; t < TT; ++t) {
    if (t < L) {
      float n0 = lse2(a0 + t00, a1 + t10) + f[2 * t];
      float n1 = lse2(a0 + t01, a1 + t11) + f[2 * t + 1];
      a0 = n0; a1 = n1;
    }
    al[2 * t] = a0; al[2 * t + 1] = a1;
  }
  float logZ = lse2(a0, a1);
  float b0 = 0.f, b1 = 0.f, ssum = 0.f;
  {
    float v = (TT - 1 < L) ? expf(al[2 * (TT - 1) + 1] - logZ) : 0.f;
    sp[b * TT + TT - 1] = v; ssum += v;
  }
  for (int t = TT - 2; t >= 0; --t) {
    float fn0 = f[2 * (t + 1)], fn1 = f[2 * (t + 1) + 1];
    float c0 = lse2(t00 + fn0 + b0, t01 + fn1 + b1);
    float c1 = lse2(t10 + fn0 + b0, t11 + fn1 + b1);
    if (t >= L - 1) { b0 = 0.f; b1 = 0.f; } else { b0 = c0; b1 = c1; }
    float v = (t < L) ? expf(al[2 * t + 1] + b1 - logZ) : 0.f;
    sp[b * TT + t] = v; ssum += v;
  }
  sp_sum[b] = ssum;
}

__global__ void k_sentv(const s16* __restrict__ ctx, const float* __restrict__ sp,
                        float* __restrict__ sv) {
  int b = blockIdx.x, t = threadIdx.x;  // 256
  float a0 = 0, a1 = 0;
  for (int tt = 0; tt < TT; ++tt) {
    float w = sp[b * TT + tt];
    if (w != 0.f) {
      a0 += w * bf2f(ctx[(size_t)(b * TT + tt) * 512 + t]);
      a1 += w * bf2f(ctx[(size_t)(b * TT + tt) * 512 + 256 + t]);
    }
  }
  sv[b * 512 + t] = a0;
  sv[b * 512 + 256 + t] = a1;
}

__global__ void k_final(const float* __restrict__ sv, const float* __restrict__ sp_sum,
                        const int* __restrict__ labels, const float* __restrict__ labw,
                        const float* __restrict__ labb, const float* __restrict__ trans,
                        float* __restrict__ out) {
  __shared__ float red[128];
  int b = threadIdx.x;  // 128
  float g = sp_sum[b] * 0.5f;
  g = fminf(fmaxf(g, 1e-4f), 1e5f);
  float s[3];
  for (int c = 0; c < 3; ++c) {
    float a = 0.f;
    for (int h = 0; h < 512; ++h) a += sv[b * 512 + h] * labw[c * 512 + h];
    s[c] = a / g + labb[c];
  }
  float m = fmaxf(s[0], fmaxf(s[1], s[2]));
  float lse = m + logf(expf(s[0] - m) + expf(s[1] - m) + expf(s[2] - m));
  red[b] = -(s[labels[b]] - lse);
  __syncthreads();
  if (b == 0) {
    float acc = 0.f, sn = 0.f;
    for (int i = 0; i < 128; ++i) { acc += red[i]; sn += sp_sum[i]; }
    float pena = fmaxf(trans[2] - trans[0], 0.f) + fmaxf(trans[1] - trans[3], 0.f);
    out[0] = acc / 128.f;
    out[1] = 0.1f * pena + 0.1f * (sn / 128.f);
  }
}

// ---------------- launcher ----------------
extern "C" void kernel_launch(void* const* d_in, const int* in_sizes, int n_in,
                              void* d_out, int out_size, void* d_ws, size_t ws_size,
                              hipStream_t stream) {
  const int*   sents  = (const int*)d_in[0];
  const int*   lens   = (const int*)d_in[1];
  const int*   masks  = (const int*)d_in[2];
  const int*   labels = (const int*)d_in[3];
  const float* wemb   = (const float*)d_in[4];
  const float* memb   = (const float*)d_in[5];
  const float* wih0f = (const float*)d_in[6],  *whh0f = (const float*)d_in[7];
  const float* bih0f = (const float*)d_in[8],  *bhh0f = (const float*)d_in[9];
  const float* wih0b = (const float*)d_in[10], *whh0b = (const float*)d_in[11];
  const float* bih0b = (const float*)d_in[12], *bhh0b = (const float*)d_in[13];
  const float* wih1f = (const float*)d_in[14], *whh1f = (const float*)d_in[15];
  const float* bih1f = (const float*)d_in[16], *bhh1f = (const float*)d_in[17];
  const float* wih1b = (const float*)d_in[18], *whh1b = (const float*)d_in[19];
  const float* bih1b = (const float*)d_in[20], *bhh1b = (const float*)d_in[21];
  const float* convw = (const float*)d_in[22], *convb = (const float*)d_in[23];
  const float* triw  = (const float*)d_in[24], *trib  = (const float*)d_in[25];
  const float* trans = (const float*)d_in[26];
  const float* labw  = (const float*)d_in[27], *labb  = (const float*)d_in[28];
  float* out = (float*)d_out;
  char* ws = (char*)d_ws;

  s16* x0    = (s16*)(ws + 0);
  s16* cwih0f = (s16*)(ws + 9011200);
  s16* cwih0b = (s16*)(ws + 9551872);
  s16* cwih1f = (s16*)(ws + 10092544);
  s16* cwih1b = (s16*)(ws + 10878976);
  s16* wf0f  = (s16*)(ws + 11665408);
  s16* wf0b  = (s16*)(ws + 12058624);
  s16* wf1f  = (s16*)(ws + 12451840);
  s16* wf1b  = (s16*)(ws + 12845056);
  s16* w2    = (s16*)(ws + 13238272);
  s16* giF   = (s16*)(ws + 14811136);
  s16* giB   = (s16*)(ws + 34471936);
  s16* x1    = (s16*)(ws + 54132736);
  s16* x2    = (s16*)(ws + 67239936);
  s16* A2    = giF;            // alias: gi dead after gru1
  s16* ctx   = x1;             // alias: x1 dead after gi1 GEMMs
  float* avg   = (float*)(ws + 80347136);
  float* tri   = (float*)(ws + 80609280);
  float* alphas= (float*)(ws + 80711680);
  float* sp    = (float*)(ws + 80814080);
  float* spsum = (float*)(ws + 80865280);
  float* sentv = (float*)(ws + 80865792);

  // prep
  k_cvtpad<<<1056, 256, 0, stream>>>(wih0f, cwih0f);
  k_cvtpad<<<1056, 256, 0, stream>>>(wih0b, cwih0b);
  k_cvt<<<1536, 256, 0, stream>>>(wih1f, cwih1f, 393216);
  k_cvt<<<1536, 256, 0, stream>>>(wih1b, cwih1b, 393216);
  k_wfrag<<<768, 256, 0, stream>>>(whh0f, wf0f);
  k_wfrag<<<768, 256, 0, stream>>>(whh0b, wf0b);
  k_wfrag<<<768, 256, 0, stream>>>(whh1f, wf1f);
  k_wfrag<<<768, 256, 0, stream>>>(whh1b, wf1b);
  k_w2<<<3072, 256, 0, stream>>>(convw, w2);
  k_embed<<<17600, 256, 0, stream>>>(sents, masks, wemb, memb, x0);
  k_zero16<<<3200, 256, 0, stream>>>((uint4*)x1, 819200);
  k_zero16<<<3200, 256, 0, stream>>>((uint4*)x2, 819200);

  // layer 0 (bih folded into gi GEMM bias)
  k_gemm<<<dim3(100, 6), 256, 0, stream>>>(x0, cwih0f, giF, 352, 352, 352, 768, bih0f, 0);
  k_gemm<<<dim3(100, 6), 256, 0, stream>>>(x0, cwih0b, giB, 352, 352, 352, 768, bih0b, 0);
  k_gru<<<dim3(16, 2), 512, 0, stream>>>(giF, giB, wf0f, wf0b, bhh0f, bhh0b, lens, x1);

  // layer 1
  k_gemm<<<dim3(100, 6), 256, 0, stream>>>(x1, cwih1f, giF, 512, 512, 512, 768, bih1f, 0);
  k_gemm<<<dim3(100, 6), 256, 0, stream>>>(x1, cwih1b, giB, 512, 512, 512, 768, bih1b, 0);
  k_gru<<<dim3(16, 2), 512, 0, stream>>>(giF, giB, wf1f, wf1b, bhh1f, bhh1b, lens, x2);

  // conv + epilogue
  k_im2col<<<9600, 256, 0, stream>>>(x2, A2);
  k_gemm<<<dim3(100, 4), 256, 0, stream>>>(A2, w2, ctx, 1536, 1536, 1536, 512, convb, 1);
  k_avg<<<128, 256, 0, stream>>>(ctx, masks, avg);
  k_tri<<<3200, 256, 0, stream>>>(ctx, avg, triw, trib, tri);
  k_crf<<<1, 128, 0, stream>>>(tri, lens, trans, alphas, sp, spsum);
  k_sentv<<<128, 256, 0, stream>>>(ctx, sp, sentv);
  k_final<<<1, 128, 0, stream>>>(sentv, spsum, labels, labw, labb, trans, out);
}

// Round 6
// 1009.658 us; speedup vs baseline: 2.7008x; 1.1319x over previous
//
#include <hip/hip_runtime.h>
#include <hip/hip_bf16.h>
#include <stdint.h>

// AspectSent forward on MI355X.
// Pipeline: k_prep (fused embed/cvt/wfrag/w2/zero) -> [gi GEMM(+bih) ->
// persistent GRU]x2 -> im2col -> conv GEMM(+relu) -> avg/tri/CRF/sentv/final.
// All matmuls bf16 MFMA 16x16x32, f32 accumulate.
// GRU v3: grid (32,2) = 4 batch rows/block, 512 thr (8 waves, 2/SIMD, 256 VGPR
// cap). whh B-frags VGPR/AGPR-resident (192 regs). gi software-pipelined ONE
// STEP AHEAD (hides ~900cy HBM latency; round-5 same-step prefetch only hid
// ~240cy). bhh folded into MFMA acc init. Gate: 1 (row,j-pair)/thread,
// row = wave/2 so len-guards are wave-uniform (no divergence).

#define TT 100
#define BB 128

typedef short s16;
typedef unsigned int u32;
typedef __attribute__((ext_vector_type(8))) short s16x8;
typedef __attribute__((ext_vector_type(4))) float f32x4;
typedef __attribute__((ext_vector_type(2))) float f32x2;

__device__ __forceinline__ float bf2f(s16 s) {
  return __uint_as_float(((unsigned)(unsigned short)s) << 16);
}
__device__ __forceinline__ s16 f2bf(float f) {
  __hip_bfloat16 h = __float2bfloat16(f);
  return *(s16*)&h;
}
__device__ __forceinline__ float sigf(float x) { return 1.f / (1.f + __expf(-x)); }
__device__ __forceinline__ float tanhfast(float x) { return 2.f / (1.f + __expf(-2.f * x)) - 1.f; }
__device__ __forceinline__ float lse2(float a, float b) {
  float m = fmaxf(a, b);
  return m + logf(expf(a - m) + expf(b - m));
}

// ---------------- fused prep (replaces 12 serial launches) ----------------
__global__ void k_prep(const float* __restrict__ wih0f, const float* __restrict__ wih0b,
                       const float* __restrict__ wih1f, const float* __restrict__ wih1b,
                       const float* __restrict__ whh0f, const float* __restrict__ whh0b,
                       const float* __restrict__ whh1f, const float* __restrict__ whh1b,
                       const float* __restrict__ convw,
                       const int* __restrict__ sents, const int* __restrict__ masks,
                       const float* __restrict__ wemb, const float* __restrict__ memb,
                       s16* __restrict__ cwih0f, s16* __restrict__ cwih0b,
                       s16* __restrict__ cwih1f, s16* __restrict__ cwih1b,
                       s16* __restrict__ wf0f, s16* __restrict__ wf0b,
                       s16* __restrict__ wf1f, s16* __restrict__ wf1b,
                       s16* __restrict__ w2, s16* __restrict__ x0,
                       uint4* __restrict__ x2z) {
  const int stride = gridDim.x * 256;
  const int base = blockIdx.x * 256 + threadIdx.x;

  // wih layer0: f32 (768x350) -> bf16 (768x352) zero-padded
  for (int idx = base; idx < 768 * 352; idx += stride) {
    int n = idx / 352, k = idx % 352;
    cwih0f[idx] = (k < 350) ? f2bf(wih0f[n * 350 + k]) : (s16)0;
    cwih0b[idx] = (k < 350) ? f2bf(wih0b[n * 350 + k]) : (s16)0;
  }
  // wih layer1: straight cvt (768x512)
  for (int idx = base; idx < 393216; idx += stride) {
    cwih1f[idx] = f2bf(wih1f[idx]);
    cwih1b[idx] = f2bf(wih1b[idx]);
  }
  // whh -> MFMA B-fragment layout (all 4 dir-layers, same index math)
  for (int idx = base; idx < 196608; idx += stride) {
    int w = idx / 24576, rem = idx % 24576;
    int f = rem / 512, rem2 = rem % 512;
    int l = rem2 / 8, i = rem2 % 8;
    int nt = f / 8, kt = f % 8;
    int src = (96 * w + 16 * nt + (l & 15)) * 256 + 32 * kt + 8 * (l >> 4) + i;
    wf0f[idx] = f2bf(whh0f[src]);
    wf0b[idx] = f2bf(whh0b[src]);
    wf1f[idx] = f2bf(whh1f[src]);
    wf1b[idx] = f2bf(whh1b[src]);
  }
  // conv_w (512,512,3) -> w2 [512][1536], w2[o][w*512+i] = conv_w[o,i,w]
  for (int idx = base; idx < 786432; idx += stride) {
    int o = idx / 1536, c = idx % 1536;
    int w = c / 512, i = c % 512;
    w2[idx] = f2bf(convw[o * 1536 + i * 3 + w]);
  }
  // embed: x0[bt][0:300]=wemb[sent], [300:350]=memb[mask], [350:352]=0
  for (int idx = base; idx < BB * TT * 352; idx += stride) {
    int c = idx % 352, bt = idx / 352;
    float v;
    if (c < 300)      v = wemb[(size_t)sents[bt] * 300 + c];
    else if (c < 350) v = memb[masks[bt] * 50 + (c - 300)];
    else              v = 0.f;
    x0[idx] = f2bf(v);
  }
  // zero x2 (conv reads t >= len; GRU1 only writes t < len)
  for (int idx = base; idx < 819200; idx += stride)
    x2z[idx] = make_uint4(0u, 0u, 0u, 0u);
}

// ---------------- GEMM: C[M,N](bf16) = A[M,K](bf16) * B[N,K](bf16)^T ----------------
// 128x128 tile, 4 waves (2x2 of 64x64), BK=32, reg-staged LDS.
__global__ __launch_bounds__(256) void k_gemm(const s16* __restrict__ A, const s16* __restrict__ Bm,
                                              s16* __restrict__ C, int K, int ldA, int ldB, int ldC,
                                              const float* __restrict__ bias, int relu) {
  __shared__ s16 As[128 * 32];
  __shared__ s16 Bs[128 * 32];
  const int t = threadIdx.x, w = t >> 6, l = t & 63;
  const size_t m0 = (size_t)blockIdx.x * 128, n0 = (size_t)blockIdx.y * 128;
  f32x4 zero = {0.f, 0.f, 0.f, 0.f};
  f32x4 acc[4][4];
#pragma unroll
  for (int i = 0; i < 4; ++i)
#pragma unroll
    for (int j = 0; j < 4; ++j) acc[i][j] = zero;

  for (int kb = 0; kb < K; kb += 32) {
    __syncthreads();
    {
      const s16* gA = A + (m0 + (t >> 1)) * (size_t)ldA + kb + 16 * (t & 1);
      *(s16x8*)&As[(t >> 1) * 32 + 16 * (t & 1)]     = *(const s16x8*)gA;
      *(s16x8*)&As[(t >> 1) * 32 + 16 * (t & 1) + 8] = *(const s16x8*)(gA + 8);
      const s16* gB = Bm + (n0 + (t >> 1)) * (size_t)ldB + kb + 16 * (t & 1);
      *(s16x8*)&Bs[(t >> 1) * 32 + 16 * (t & 1)]     = *(const s16x8*)gB;
      *(s16x8*)&Bs[(t >> 1) * 32 + 16 * (t & 1) + 8] = *(const s16x8*)(gB + 8);
    }
    __syncthreads();
    s16x8 a[4], b[4];
#pragma unroll
    for (int i = 0; i < 4; ++i)
      a[i] = *(const s16x8*)&As[(64 * (w >> 1) + 16 * i + (l & 15)) * 32 + 8 * (l >> 4)];
#pragma unroll
    for (int j = 0; j < 4; ++j)
      b[j] = *(const s16x8*)&Bs[(64 * (w & 1) + 16 * j + (l & 15)) * 32 + 8 * (l >> 4)];
#pragma unroll
    for (int i = 0; i < 4; ++i)
#pragma unroll
      for (int j = 0; j < 4; ++j)
        acc[i][j] = __builtin_amdgcn_mfma_f32_16x16x32_bf16(a[i], b[j], acc[i][j], 0, 0, 0);
  }
#pragma unroll
  for (int i = 0; i < 4; ++i)
#pragma unroll
    for (int j = 0; j < 4; ++j)
#pragma unroll
      for (int r = 0; r < 4; ++r) {
        size_t row = m0 + 64 * (w >> 1) + 16 * i + 4 * (l >> 4) + r;
        size_t col = n0 + 64 * (w & 1) + 16 * j + (l & 15);
        float v = acc[i][j][r];
        if (bias) v += bias[col];
        if (relu) v = fmaxf(v, 0.f);
        C[row * (size_t)ldC + col] = f2bf(v);
      }
}

// ---------------- persistent GRU v3 ----------------
// grid (32,2): blockIdx.x = 4-row group, blockIdx.y = dir. 512 thr = 8 waves;
// wave w owns gh cols [96w,96w+96): 48 whh B-frags in 192 regs. bhh folded
// into acc init. gi pipelined one step ahead. Gate: row = wave/2 (uniform).
__global__ __launch_bounds__(512, 2) void k_gru(
    const s16* __restrict__ gi_f, const s16* __restrict__ gi_b,
    const s16* __restrict__ wf_f, const s16* __restrict__ wf_b,
    const float* __restrict__ bhh_f, const float* __restrict__ bhh_b,
    const int* __restrict__ lens, s16* __restrict__ out) {
  const int g = blockIdx.x;
  const int dir = blockIdx.y;
  const int tid = threadIdx.x, wid = tid >> 6, l = tid & 63;
  const s16* gi = dir ? gi_b : gi_f;
  const s16* wf = dir ? wf_b : wf_f;
  const float* bhh = dir ? bhh_b : bhh_f;
  const int col_off = dir ? 256 : 0;
  const int b0 = g * 4;

  __shared__ __align__(16) float gh2[16 * 772];  // rows 4..15 written, unused
  __shared__ __align__(16) s16 hb[16 * 264];     // rows 4..15 stay zero
  __shared__ int s_len[4];

  // whh B-fragments, register-resident (192 regs; MFMA reads VGPR or AGPR)
  s16x8 wv[48];
#pragma unroll
  for (int f = 0; f < 48; ++f)
    wv[f] = *(const s16x8*)&wf[((size_t)(wid * 48 + f)) * 512 + l * 8];
  // bhh broadcast values for acc init (col = 96wid+16nt+(l&15))
  float bv[6];
#pragma unroll
  for (int nt = 0; nt < 6; ++nt) bv[nt] = bhh[96 * wid + 16 * nt + (l & 15)];

  for (int i = tid; i < 16 * 264; i += 512) hb[i] = 0;
  if (tid < 4) s_len[tid] = lens[b0 + tid];
  __syncthreads();

  const int smax = s_len[0];          // lens sorted descending
  const int row = tid >> 7;           // 0..3 == wave/2 (wave-uniform)
  const int j0 = (tid & 127) * 2;
  const int len = s_len[row];
  const s16* gbase = gi + (size_t)(b0 + row) * TT * 768 + j0;
  s16* obase = out + (size_t)(b0 + row) * TT * 512 + col_off + j0;
  float hp0 = 0.f, hp1 = 0.f;

  // prologue: prefetch gi for s=0 (len >= 5 always)
  u32 qa0, qa1, qa2;
  int pa;
  {
    pa = dir ? (len - 1) : 0;
    const s16* gp = gbase + (size_t)pa * 768;
    qa0 = *(const u32*)gp; qa1 = *(const u32*)(gp + 256); qa2 = *(const u32*)(gp + 512);
  }

  for (int s = 0; s < smax; ++s) {
    // ---- issue prefetch for step s+1 (consumed next iteration) ----
    u32 qb0 = 0, qb1 = 0, qb2 = 0;
    int pb = 0;
    if (s + 1 < len) {
      pb = dir ? (len - 2 - s) : (s + 1);
      const s16* gp = gbase + (size_t)pb * 768;
      qb0 = *(const u32*)gp; qb1 = *(const u32*)(gp + 256); qb2 = *(const u32*)(gp + 512);
    }

    // ---- MFMA phase: gh = hb @ whh^T + bhh ----
    f32x4 acc[6];
#pragma unroll
    for (int nt = 0; nt < 6; ++nt) { f32x4 b = {bv[nt], bv[nt], bv[nt], bv[nt]}; acc[nt] = b; }
#pragma unroll
    for (int kt = 0; kt < 8; ++kt) {
      s16x8 a = *(const s16x8*)&hb[(l & 15) * 264 + 32 * kt + 8 * (l >> 4)];
#pragma unroll
      for (int nt = 0; nt < 6; ++nt)
        acc[nt] = __builtin_amdgcn_mfma_f32_16x16x32_bf16(a, wv[nt * 8 + kt], acc[nt], 0, 0, 0);
    }
#pragma unroll
    for (int nt = 0; nt < 6; ++nt) {
      int col = 96 * wid + 16 * nt + (l & 15);
#pragma unroll
      for (int r = 0; r < 4; ++r)
        gh2[(4 * (l >> 4) + r) * 772 + col] = acc[nt][r];
    }
    __syncthreads();

    // ---- gate phase (wave-uniform guard) ----
    if (s < len) {
      f32x2 gr = *(const f32x2*)&gh2[row * 772 + j0];
      f32x2 gz = *(const f32x2*)&gh2[row * 772 + 256 + j0];
      f32x2 gn = *(const f32x2*)&gh2[row * 772 + 512 + j0];
      float rr0 = sigf(bf2f((s16)(qa0 & 0xffff)) + gr[0]);
      float rr1 = sigf(bf2f((s16)(qa0 >> 16))    + gr[1]);
      float zz0 = sigf(bf2f((s16)(qa1 & 0xffff)) + gz[0]);
      float zz1 = sigf(bf2f((s16)(qa1 >> 16))    + gz[1]);
      float nn0 = tanhfast(bf2f((s16)(qa2 & 0xffff)) + rr0 * gn[0]);
      float nn1 = tanhfast(bf2f((s16)(qa2 >> 16))    + rr1 * gn[1]);
      hp0 = (1.f - zz0) * nn0 + zz0 * hp0;
      hp1 = (1.f - zz1) * nn1 + zz1 * hp1;
      u32 pk = (u32)(unsigned short)f2bf(hp0) | ((u32)(unsigned short)f2bf(hp1) << 16);
      *(u32*)&hb[row * 264 + j0] = pk;
      *(u32*)&obase[(size_t)pa * 512] = pk;
    }
    __syncthreads();
    qa0 = qb0; qa1 = qb1; qa2 = qb2; pa = pb;
  }
}

// ---------------- im2col for conv (k=3, pad 1) ----------------
__global__ void k_im2col(const s16* __restrict__ x2, s16* __restrict__ A2) {
  int idx = blockIdx.x * 256 + threadIdx.x;           // 12800*1536/8
  if (idx >= 2457600) return;
  size_t e = (size_t)idx * 8;
  int bt = (int)(e / 1536), c = (int)(e % 1536);
  int w = c / 512, i = c % 512;
  int b = bt / TT, t = bt % TT;
  int ts = t + w - 1;
  s16x8 v;
  if (ts >= 0 && ts < TT) v = *(const s16x8*)&x2[(size_t)(b * TT + ts) * 512 + i];
  else { s16x8 z = {0,0,0,0,0,0,0,0}; v = z; }
  *(s16x8*)&A2[e] = v;
}

// ---------------- small epilogue kernels ----------------
__global__ void k_avg(const s16* __restrict__ ctx, const int* __restrict__ masks,
                      float* __restrict__ avg) {
  int b = blockIdx.x, t = threadIdx.x;  // 256
  float a0 = 0, a1 = 0, ms = 0;
  for (int tt = 0; tt < TT; ++tt) {
    float mf = (float)masks[b * TT + tt];
    ms += mf;
    if (mf != 0.f) {
      a0 += mf * bf2f(ctx[(size_t)(b * TT + tt) * 512 + t]);
      a1 += mf * bf2f(ctx[(size_t)(b * TT + tt) * 512 + 256 + t]);
    }
  }
  avg[b * 512 + t] = a0 / ms;
  avg[b * 512 + 256 + t] = a1 / ms;
}

__global__ void k_tri(const s16* __restrict__ ctx, const float* __restrict__ avg,
                      const float* __restrict__ triw, const float* __restrict__ trib,
                      float* __restrict__ tri) {
  int gw = (blockIdx.x * 256 + threadIdx.x) >> 6;
  int l = threadIdx.x & 63;
  if (gw >= BB * TT) return;
  int b = gw / TT;
  float a0 = 0, a1 = 0;
  for (int it = 0; it < 16; ++it) {
    int k = l + 64 * it;
    float v = (k < 512) ? bf2f(ctx[(size_t)gw * 512 + k]) : avg[b * 512 + k - 512];
    a0 += v * triw[k];
    a1 += v * triw[1024 + k];
  }
  for (int off = 32; off; off >>= 1) {
    a0 += __shfl_down(a0, off, 64);
    a1 += __shfl_down(a1, off, 64);
  }
  if (l == 0) {
    tri[gw * 2]     = a0 + trib[0];
    tri[gw * 2 + 1] = a1 + trib[1];
  }
}

__global__ void k_crf(const float* __restrict__ tri, const int* __restrict__ lens,
                      const float* __restrict__ trans, float* __restrict__ alphas,
                      float* __restrict__ sp, float* __restrict__ sp_sum) {
  int b = threadIdx.x;  // 128 threads, 1 block
  int L = lens[b];
  float t00 = trans[0], t01 = trans[1], t10 = trans[2], t11 = trans[3];
  const float* f = tri + b * 2 * TT;
  float* al = alphas + b * 2 * TT;
  float a0 = f[0], a1 = f[1];
  al[0] = a0; al[1] = a1;
  for (int t = 1; t < TT; ++t) {
    if (t < L) {
      float n0 = lse2(a0 + t00, a1 + t10) + f[2 * t];
      float n1 = lse2(a0 + t01, a1 + t11) + f[2 * t + 1];
      a0 = n0; a1 = n1;
    }
    al[2 * t] = a0; al[2 * t + 1] = a1;
  }
  float logZ = lse2(a0, a1);
  float b0 = 0.f, b1 = 0.f, ssum = 0.f;
  {
    float v = (TT - 1 < L) ? expf(al[2 * (TT - 1) + 1] - logZ) : 0.f;
    sp[b * TT + TT - 1] = v; ssum += v;
  }
  for (int t = TT - 2; t >= 0; --t) {
    float fn0 = f[2 * (t + 1)], fn1 = f[2 * (t + 1) + 1];
    float c0 = lse2(t00 + fn0 + b0, t01 + fn1 + b1);
    float c1 = lse2(t10 + fn0 + b0, t11 + fn1 + b1);
    if (t >= L - 1) { b0 = 0.f; b1 = 0.f; } else { b0 = c0; b1 = c1; }
    float v = (t < L) ? expf(al[2 * t + 1] + b1 - logZ) : 0.f;
    sp[b * TT + t] = v; ssum += v;
  }
  sp_sum[b] = ssum;
}

__global__ void k_sentv(const s16* __restrict__ ctx, const float* __restrict__ sp,
                        float* __restrict__ sv) {
  int b = blockIdx.x, t = threadIdx.x;  // 256
  float a0 = 0, a1 = 0;
  for (int tt = 0; tt < TT; ++tt) {
    float w = sp[b * TT + tt];
    if (w != 0.f) {
      a0 += w * bf2f(ctx[(size_t)(b * TT + tt) * 512 + t]);
      a1 += w * bf2f(ctx[(size_t)(b * TT + tt) * 512 + 256 + t]);
    }
  }
  sv[b * 512 + t] = a0;
  sv[b * 512 + 256 + t] = a1;
}

__global__ void k_final(const float* __restrict__ sv, const float* __restrict__ sp_sum,
                        const int* __restrict__ labels, const float* __restrict__ labw,
                        const float* __restrict__ labb, const float* __restrict__ trans,
                        float* __restrict__ out) {
  __shared__ float red[128];
  int b = threadIdx.x;  // 128
  float g = sp_sum[b] * 0.5f;
  g = fminf(fmaxf(g, 1e-4f), 1e5f);
  float s[3];
  for (int c = 0; c < 3; ++c) {
    float a = 0.f;
    for (int h = 0; h < 512; ++h) a += sv[b * 512 + h] * labw[c * 512 + h];
    s[c] = a / g + labb[c];
  }
  float m = fmaxf(s[0], fmaxf(s[1], s[2]));
  float lse = m + logf(expf(s[0] - m) + expf(s[1] - m) + expf(s[2] - m));
  red[b] = -(s[labels[b]] - lse);
  __syncthreads();
  if (b == 0) {
    float acc = 0.f, sn = 0.f;
    for (int i = 0; i < 128; ++i) { acc += red[i]; sn += sp_sum[i]; }
    float pena = fmaxf(trans[2] - trans[0], 0.f) + fmaxf(trans[1] - trans[3], 0.f);
    out[0] = acc / 128.f;
    out[1] = 0.1f * pena + 0.1f * (sn / 128.f);
  }
}

// ---------------- launcher ----------------
extern "C" void kernel_launch(void* const* d_in, const int* in_sizes, int n_in,
                              void* d_out, int out_size, void* d_ws, size_t ws_size,
                              hipStream_t stream) {
  const int*   sents  = (const int*)d_in[0];
  const int*   lens   = (const int*)d_in[1];
  const int*   masks  = (const int*)d_in[2];
  const int*   labels = (const int*)d_in[3];
  const float* wemb   = (const float*)d_in[4];
  const float* memb   = (const float*)d_in[5];
  const float* wih0f = (const float*)d_in[6],  *whh0f = (const float*)d_in[7];
  const float* bih0f = (const float*)d_in[8],  *bhh0f = (const float*)d_in[9];
  const float* wih0b = (const float*)d_in[10], *whh0b = (const float*)d_in[11];
  const float* bih0b = (const float*)d_in[12], *bhh0b = (const float*)d_in[13];
  const float* wih1f = (const float*)d_in[14], *whh1f = (const float*)d_in[15];
  const float* bih1f = (const float*)d_in[16], *bhh1f = (const float*)d_in[17];
  const float* wih1b = (const float*)d_in[18], *whh1b = (const float*)d_in[19];
  const float* bih1b = (const float*)d_in[20], *bhh1b = (const float*)d_in[21];
  const float* convw = (const float*)d_in[22], *convb = (const float*)d_in[23];
  const float* triw  = (const float*)d_in[24], *trib  = (const float*)d_in[25];
  const float* trans = (const float*)d_in[26];
  const float* labw  = (const float*)d_in[27], *labb  = (const float*)d_in[28];
  float* out = (float*)d_out;
  char* ws = (char*)d_ws;

  s16* x0    = (s16*)(ws + 0);
  s16* cwih0f = (s16*)(ws + 9011200);
  s16* cwih0b = (s16*)(ws + 9551872);
  s16* cwih1f = (s16*)(ws + 10092544);
  s16* cwih1b = (s16*)(ws + 10878976);
  s16* wf0f  = (s16*)(ws + 11665408);
  s16* wf0b  = (s16*)(ws + 12058624);
  s16* wf1f  = (s16*)(ws + 12451840);
  s16* wf1b  = (s16*)(ws + 12845056);
  s16* w2    = (s16*)(ws + 13238272);
  s16* giF   = (s16*)(ws + 14811136);
  s16* giB   = (s16*)(ws + 34471936);
  s16* x1    = (s16*)(ws + 54132736);
  s16* x2    = (s16*)(ws + 67239936);
  s16* A2    = giF;            // alias: gi dead after gru1
  s16* ctx   = x1;             // alias: x1 dead after gi1 GEMMs
  float* avg   = (float*)(ws + 80347136);
  float* tri   = (float*)(ws + 80609280);
  float* alphas= (float*)(ws + 80711680);
  float* sp    = (float*)(ws + 80814080);
  float* spsum = (float*)(ws + 80865280);
  float* sentv = (float*)(ws + 80865792);

  // fused prep (embed, weight cvt/fragment, conv repack, x2 zero)
  k_prep<<<2048, 256, 0, stream>>>(wih0f, wih0b, wih1f, wih1b,
                                   whh0f, whh0b, whh1f, whh1b, convw,
                                   sents, masks, wemb, memb,
                                   cwih0f, cwih0b, cwih1f, cwih1b,
                                   wf0f, wf0b, wf1f, wf1b, w2, x0, (uint4*)x2);

  // layer 0 (bih folded into gi GEMM bias)
  k_gemm<<<dim3(100, 6), 256, 0, stream>>>(x0, cwih0f, giF, 352, 352, 352, 768, bih0f, 0);
  k_gemm<<<dim3(100, 6), 256, 0, stream>>>(x0, cwih0b, giB, 352, 352, 352, 768, bih0b, 0);
  k_gru<<<dim3(32, 2), 512, 0, stream>>>(giF, giB, wf0f, wf0b, bhh0f, bhh0b, lens, x1);

  // layer 1
  k_gemm<<<dim3(100, 6), 256, 0, stream>>>(x1, cwih1f, giF, 512, 512, 512, 768, bih1f, 0);
  k_gemm<<<dim3(100, 6), 256, 0, stream>>>(x1, cwih1b, giB, 512, 512, 512, 768, bih1b, 0);
  k_gru<<<dim3(32, 2), 512, 0, stream>>>(giF, giB, wf1f, wf1b, bhh1f, bhh1b, lens, x2);

  // conv + epilogue
  k_im2col<<<9600, 256, 0, stream>>>(x2, A2);
  k_gemm<<<dim3(100, 4), 256, 0, stream>>>(A2, w2, ctx, 1536, 1536, 1536, 512, convb, 1);
  k_avg<<<128, 256, 0, stream>>>(ctx, masks, avg);
  k_tri<<<3200, 256, 0, stream>>>(ctx, avg, triw, trib, tri);
  k_crf<<<1, 128, 0, stream>>>(tri, lens, trans, alphas, sp, spsum);
  k_sentv<<<128, 256, 0, stream>>>(ctx, sp, sentv);
  k_final<<<1, 128, 0, stream>>>(sentv, spsum, labels, labw, labb, trans, out);
}